// Round 6
// baseline (256.593 us; speedup 1.0000x reference)
//
#include <hip/hip_runtime.h>
#include <math.h>

// x: (16, 512, 512, 8) float32 NHWC. float4 granule: ((n*512+h)*512+w)*2+c4.
//
// v6: PHASE-SPLIT STREAMS (decisive experiment). R0-R5: five structures
// (occupancy 25-76%, MLP 1-30KB/wave, LDS/reg, barriers/none) ALL pin at
// 80-87us, 2.5-2.6 TB/s HBM, every pipe <40%. The untested axis: all
// variants run a fine-grained MIXED read+write stream chip-wide; the
// harness's own pure-write fill does 6.6 TB/s. Launch A: pure-read warm
// sweep of x (unmixed read stream; parks input in the 256MB LLC — input
// is 134MB but the 537MB inter-iteration poison-fill evicts it every
// time). Launch B: v4b unchanged; its reads should now hit LLC and its
// NT-write stream runs ~unmixed to HBM.
// If A itself runs at ~1.7TB/s, the read path is the ceiling -> revert,
// declare roofline with that evidence.

constexpr int Hdim = 512;
constexpr int Wdim = 512;
constexpr int ROW  = Wdim * 2;       // f4 stride between h rows
constexpr int TH   = 8;              // output rows per block
constexpr int TW   = 64;             // w positions per block
constexpr int LROWS = TH + 2;        // 10 staged rows (1 halo each side)
constexpr int LCOLS = TW * 2 + 4;    // 132 f4 per LDS row (2 halo f4 each side)

typedef float floatx4 __attribute__((ext_vector_type(4)));

__device__ __forceinline__ float4 f4max(float4 a, float4 b) {
    return make_float4(fmaxf(a.x,b.x), fmaxf(a.y,b.y), fmaxf(a.z,b.z), fmaxf(a.w,b.w));
}

__device__ __forceinline__ void nt_store_f4(float4* p, float4 v) {
    floatx4 nv; nv.x = v.x; nv.y = v.y; nv.z = v.z; nv.w = v.w;
    __builtin_nontemporal_store(nv, reinterpret_cast<floatx4*>(p));
}

// ---- Launch A: pure-read warm sweep. 2048 blocks x 256 threads; each
// thread reads 16 f4 at stride 524288 f4 (fully coalesced, 16KB/wave in
// flight). Keep-alive asm defeats DCE. No stores -> unmixed read stream.
__global__ __launch_bounds__(256) void warm_kernel(const float4* __restrict__ x) {
    int tid = blockIdx.x * 256 + threadIdx.x;       // 0..524287
    float4 acc = x[tid];
    #pragma unroll
    for (int k = 1; k < 16; ++k)
        acc = f4max(acc, x[tid + k * 524288]);      // 16*524288 = 8.39M f4 = whole x
    asm volatile("" :: "v"(acc.x), "v"(acc.y), "v"(acc.z), "v"(acc.w));
}

__global__ __launch_bounds__(256, 7) void nms_kernel(
    const float4* __restrict__ x,
    const unsigned char* __restrict__ mask_bytes,
    float4* __restrict__ out)
{
    __shared__ float4 lds[LROWS][LCOLS];   // 10*132*16 = 21120 B

    // ---- Decode 3x3 boolean mask robustly (int32 vs 1-byte bool layout).
    const int* mi = (const int*)mask_bytes;
    bool intlay = true;
    #pragma unroll
    for (int i = 0; i < 9; ++i) { int v = mi[i]; intlay = intlay && (v == 0 || v == 1); }
    bool m[9];
    #pragma unroll
    for (int i = 0; i < 9; ++i) m[i] = intlay ? (mi[i] != 0) : (mask_bytes[i] != 0);

    const float4 NEG = make_float4(-INFINITY, -INFINITY, -INFINITY, -INFINITY);

    int b  = blockIdx.x;
    int wg = b & 7;            // 8 w-groups of 64
    int hg = (b >> 3) & 63;    // 64 h-groups of 8
    int n  = b >> 9;
    int h0 = hg * TH;
    int w0 = wg * TW;
    int t  = threadIdx.x;

    // ---- Stage main tile: 10 rows x 128 f4, 5 loads/thread, coalesced.
    int gb = ((n * Hdim + (h0 - 1)) * Wdim + w0) * 2;  // f4 of (row 0, col 0)
    #pragma unroll
    for (int i = 0; i < 5; ++i) {
        int idx = t + i * 256;
        int r = idx >> 7;          // 0..9
        int c = idx & 127;         // 0..127
        int h = h0 - 1 + r;
        float4 v = NEG;
        if (h >= 0 && h < Hdim)    // block/group-uniform branch
            v = x[gb + r * ROW + c];
        lds[r][2 + c] = v;
    }
    // ---- Halo cols: 10 rows x {w0-1, w0+64} x 2 c4 = 40 f4.
    if (t < 40) {
        int r    = t >> 2;
        int q    = t & 3;
        int side = q >> 1;         // 0 = low (w0-1), 1 = high (w0+64)
        int c4   = q & 1;
        int h    = h0 - 1 + r;
        int wgl  = side ? (w0 + TW) : (w0 - 1);
        float4 v = NEG;
        if (h >= 0 && h < Hdim && wgl >= 0 && wgl < Wdim)
            v = x[((n * Hdim + h) * Wdim + wgl) * 2 + c4];
        lds[r][side ? (2 + 2 * TW + c4) : c4] = v;
    }
    __syncthreads();

    // ---- Compute: thread owns 4 consecutive output rows at one (w, c4).
    int cidx = t & 127;            // main col 0..127
    int hb   = (t >> 7) * 4;       // first window-row (LDS index) 0 or 4
    int col  = 2 + cidx;
    int obase = ((n * Hdim + h0) * Wdim + w0) * 2 + cidx;

    float4 R0a = NEG, R0b = NEG, R1b = NEG, CTb = NEG;
    #pragma unroll
    for (int k = 0; k < 6; ++k) {
        int r = hb + k;
        float4 a  = lds[r][col - 2];
        float4 bb = lds[r][col];
        float4 cc = lds[r][col + 2];

        float4 R0 = NEG, R1 = NEG, R2 = NEG;
        if (m[0]) R0 = f4max(R0, a);
        if (m[1]) R0 = f4max(R0, bb);
        if (m[2]) R0 = f4max(R0, cc);
        if (m[3]) R1 = f4max(R1, a);
        if (m[4]) R1 = f4max(R1, bb);
        if (m[5]) R1 = f4max(R1, cc);
        if (m[6]) R2 = f4max(R2, a);
        if (m[7]) R2 = f4max(R2, bb);
        if (m[8]) R2 = f4max(R2, cc);

        if (k >= 2) {
            float4 mm  = f4max(f4max(R0a, R1b), R2);
            float4 ctr = CTb;
            float4 o;
            o.x = (ctr.x > mm.x) ? ctr.x : 0.0f;
            o.y = (ctr.y > mm.y) ? ctr.y : 0.0f;
            o.z = (ctr.z > mm.z) ? ctr.z : 0.0f;
            o.w = (ctr.w > mm.w) ? ctr.w : 0.0f;
            nt_store_f4(&out[obase + (hb + k - 2) * ROW], o);
        }
        R0a = R0b; R0b = R0; R1b = R1; CTb = bb;
    }
}

extern "C" void kernel_launch(void* const* d_in, const int* in_sizes, int n_in,
                              void* d_out, int out_size, void* d_ws, size_t ws_size,
                              hipStream_t stream) {
    const float4* x = (const float4*)d_in[0];
    const unsigned char* mask = (const unsigned char*)d_in[1];
    float4* out = (float4*)d_out;

    // Phase A: unmixed read stream; parks input in LLC.
    warm_kernel<<<2048, 256, 0, stream>>>(x);
    // Phase B: compute; reads hit LLC, NT writes stream to HBM.
    int grid = 16 * (Hdim / TH) * (Wdim / TW);   // 8192
    nms_kernel<<<grid, 256, 0, stream>>>(x, mask, out);
}